// Round 16
// baseline (65.732 us; speedup 1.0000x reference)
//
#include <hip/hip_runtime.h>

// x[2][4][128][128][128] f32, y[2][1][128][128][128] int32
constexpr int SPB = 1 << 21;
constexpr float EPSV = 1e-6f;

// Static scratch: packed per-voxel mask, 4 MB.
// mask[v] = (center_class << 4) | OR_{3x3x3 clipped}(1 << y[v+d])
__device__ unsigned char g_mask[2 * SPB];

// ===========================================================================
// K0: build packed 27-neighborhood presence mask + center class (proven R5)
// ===========================================================================
constexpr int K0_ZSEG = 4;
constexpr int K0_NBLK = (2 * (128 / K0_ZSEG) * 128) / 4;  // 2048

struct MEnt { int pk, cx, cy; };

__device__ __forceinline__ MEnt k0_load(const int* __restrict__ yb, int s,
                                        int rbase0, bool ym1, bool yp1) {
    MEnt e;
    const int rb = (s << 14) | rbase0;
    int2 vc = *(const int2*)(yb + rb);
    int nib0 = 1 << vc.x, nib1 = 1 << vc.y;
    if (ym1) { int2 vm = *(const int2*)(yb + rb - 128); nib0 |= 1 << vm.x; nib1 |= 1 << vm.y; }
    if (yp1) { int2 vp = *(const int2*)(yb + rb + 128); nib0 |= 1 << vp.x; nib1 |= 1 << vp.y; }
    e.pk = nib0 | (nib1 << 8);
    e.cx = vc.x; e.cy = vc.y;
    return e;
}

__global__ __launch_bounds__(256) void mask_build(const int* __restrict__ y32) {
    const int wid = (blockIdx.x << 2) | (threadIdx.x >> 6);
    const int lane = threadIdx.x & 63;
    const int yy = wid & 127;
    const int zs = (wid >> 7) & 31;
    const int b = (wid >> 12) & 1;
    const int x0 = lane << 1;
    const int z0 = zs * K0_ZSEG;
    const bool ym1 = yy > 0, yp1 = yy < 127;
    const int rbase0 = (yy << 7) | x0;

    const int* __restrict__ yb = y32 + ((long)b << 21);
    unsigned char* __restrict__ mb = g_mask + ((long)b << 21);

    MEnt e0, e1;
    if (z0 > 0) e0 = k0_load(yb, z0 - 1, rbase0, ym1, yp1);
    else { e0.pk = 0; e0.cx = 0; e0.cy = 0; }
    e1 = k0_load(yb, z0, rbase0, ym1, yp1);

#pragma unroll
    for (int dz = 0; dz < K0_ZSEG; ++dz) {
        const int z = z0 + dz;
        MEnt e2;
        if (z + 1 < 128) e2 = k0_load(yb, z + 1, rbase0, ym1, yp1);
        else { e2.pk = 0; e2.cx = 0; e2.cy = 0; }

        const int zor = e0.pk | e1.pk | e2.pk;
        int orL = __shfl_up(zor, 1);
        if (lane == 0) orL = 0;
        int orR = __shfl_down(zor, 1);
        if (lane == 63) orR = 0;
        const int full0 = (zor | (zor >> 8) | (orL >> 8)) & 15;
        const int full1 = (zor | (zor >> 8) | orR) & 15;

        const unsigned short st =
            (unsigned short)((full0 | (e1.cx << 4)) | ((full1 | (e1.cy << 4)) << 8));
        *(unsigned short*)(mb + ((z << 14) | rbase0)) = st;

        e0 = e1; e1 = e2;
    }
}

// ===========================================================================
// K1: Y-MARCHING stencil — every load stream advances +512 B/step (page-dense,
// mask_build's pattern). Wave = (plane, z-pair, 8-row y-chunk). 6 streams:
// slices z-1..z+2 (float2 of x) + masks of slices z, z+1 (ushort). 3-row
// register rings; no LDS data path, no barriers, no launch-bounds squeeze.
// ===========================================================================
constexpr int NBLK = 2048;   // 8 planes * 16 z-quads * 16 y-chunks

__global__ __launch_bounds__(256) void lah_y(const float* __restrict__ x,
                                             float* __restrict__ acc) {
    __shared__ float sred[4];

    const int bid = blockIdx.x;
    const int plane = bid & 7;            // -> XCD (round-robin dispatch)
    const int b = plane >> 2, cls = plane & 3;
    const int inner = bid >> 3;           // 0..255
    const int zq = inner & 15;            // 4 z-pairs per block (consecutive)
    const int yc = inner >> 4;            // 0..15
    const int t = threadIdx.x;
    const int w = t >> 6;
    const int lane = t & 63;
    const int zp = zq * 4 + w;            // z-pair 0..63
    const int z0 = zp * 2;                // output slices z0, z0+1
    const int y0 = yc * 8;
    const int xo = lane << 1;

    const float* __restrict__ xp = x + ((long)plane << 21);
    const unsigned char* __restrict__ mb = g_mask + ((long)b << 21);

    const bool s0ok = (z0 > 0);           // stream 0 = slice z0-1
    const bool s3ok = (z0 + 2 < 128);     // stream 3 = slice z0+2

    // (1-x) pair of stream s (slice z0-1+s) at row y; OOB -> 1
    auto ldr = [&](int s, int y) -> float2 {
        const bool ok = (s == 0 ? s0ok : (s == 3 ? s3ok : true)) &&
                        ((unsigned)y <= 127u);
        if (!ok) return make_float2(1.f, 1.f);
        const float2 v = *(const float2*)(xp + ((z0 - 1 + s) << 14) + (y << 7) + xo);
        return make_float2(1.f - v.x, 1.f - v.y);
    };

    float fp = 0.f, fn = 0.f, sx = 0.f, sy = 0.f;

    // ring: om[s][0..2] = (1-x) rows y-1, y, y+1 of stream s
    float2 om[4][3];
#pragma unroll
    for (int s = 0; s < 4; ++s) {
        om[s][0] = ldr(s, y0 - 1);
        om[s][1] = ldr(s, y0);
    }

#pragma unroll
    for (int dy = 0; dy < 8; ++dy) {
        const int y = y0 + dy;

        // advance all 6 streams (+512 B x-streams, +128 B mask streams)
#pragma unroll
        for (int s = 0; s < 4; ++s) om[s][2] = ldr(s, y + 1);
        const unsigned mA = *(const unsigned short*)(mb + (z0 << 14) + (y << 7) + xo);
        const unsigned mB = *(const unsigned short*)(mb + ((z0 + 1) << 14) + (y << 7) + xo);

        // y-products per stream
        float ypx[4], ypy[4];
#pragma unroll
        for (int s = 0; s < 4; ++s) {
            ypx[s] = om[s][0].x * om[s][1].x * om[s][2].x;
            ypy[s] = om[s][0].y * om[s][1].y * om[s][2].y;
        }

        // z-products for the two output slices
        const float zAx = ypx[0] * ypx[1] * ypx[2];
        const float zAy = ypy[0] * ypy[1] * ypy[2];
        const float zBx = ypx[1] * ypx[2] * ypx[3];
        const float zBy = ypy[1] * ypy[2] * ypy[3];

        // x-direction via shuffles
        float lA = __shfl_up(zAy, 1);   if (lane == 0)  lA = 1.f;
        float rA = __shfl_down(zAx, 1); if (lane == 63) rA = 1.f;
        float lB = __shfl_up(zBy, 1);   if (lane == 0)  lB = 1.f;
        float rB = __shfl_down(zBx, 1); if (lane == 63) rB = 1.f;
        const float cA = zAx * zAy, cB = zBx * zBy;
        const float PA0 = lA * cA, PA1 = cA * rA;
        const float PB0 = lB * cB, PB1 = cB * rB;

        // center raw x: slice z0 -> 1-om[1][1], slice z0+1 -> 1-om[2][1]
        const float xA0 = 1.f - om[1][1].x, xA1 = 1.f - om[1][1].y;
        const float xB0 = 1.f - om[2][1].x, xB1 = 1.f - om[2][1].y;

        {
            const int m0 = mA & 0xFF, m1 = (mA >> 8) & 0xFF;
            const bool pr0 = (m0 >> cls) & 1, pr1 = (m1 >> cls) & 1;
            const bool eq0 = (m0 >> 4) == cls, eq1 = (m1 >> 4) == cls;
            sx += xA0 + xA1;
            fp += eq0 ? 0.f : xA0 * (pr0 ? 1.f : 2.f);
            fp += eq1 ? 0.f : xA1 * (pr1 ? 1.f : 2.f);
            fn += eq0 ? om[1][1].x * (1.f + PA0) : 0.f;
            fn += eq1 ? om[1][1].y * (1.f + PA1) : 0.f;
            sy += (eq0 ? 1.f : 0.f) + (eq1 ? 1.f : 0.f);
        }
        {
            const int m0 = mB & 0xFF, m1 = (mB >> 8) & 0xFF;
            const bool pr0 = (m0 >> cls) & 1, pr1 = (m1 >> cls) & 1;
            const bool eq0 = (m0 >> 4) == cls, eq1 = (m1 >> 4) == cls;
            sx += xB0 + xB1;
            fp += eq0 ? 0.f : xB0 * (pr0 ? 1.f : 2.f);
            fp += eq1 ? 0.f : xB1 * (pr1 ? 1.f : 2.f);
            fn += eq0 ? om[2][1].x * (1.f + PB0) : 0.f;
            fn += eq1 ? om[2][1].y * (1.f + PB1) : 0.f;
            sy += (eq0 ? 1.f : 0.f) + (eq1 ? 1.f : 0.f);
        }

        // rotate rings
#pragma unroll
        for (int s = 0; s < 4; ++s) {
            om[s][0] = om[s][1];
            om[s][1] = om[s][2];
        }
    }

    // ---- reduce 4 scalars: wave shuffle -> block LDS -> global atomics ----
    float rr4[4] = {fp, fn, sx, sy};
#pragma unroll
    for (int i = 0; i < 4; ++i) {
        float vv = rr4[i];
#pragma unroll
        for (int off = 32; off >= 1; off >>= 1) vv += __shfl_down(vv, off);
        rr4[i] = vv;
    }
    if (t < 4) sred[t] = 0.f;
    __syncthreads();
    if (lane == 0) {
#pragma unroll
        for (int i = 0; i < 4; ++i) atomicAdd(&sred[i], rr4[i]);
    }
    __syncthreads();
    if (t < 4)
        atomicAdd(&acc[b * 16 + t * 4 + cls], sred[t]);
}

// ===========================================================================
// K2: finalize scalar loss
// ===========================================================================
__global__ void lah_finalize(const float* __restrict__ acc, float* __restrict__ out) {
    float loss = 0.f;
#pragma unroll
    for (int b = 0; b < 2; ++b) {
#pragma unroll
        for (int c = 1; c < 4; ++c) {
            const float fp = acc[b * 16 + 0 + c];
            const float fn = acc[b * 16 + 4 + c];
            const float sxv = acc[b * 16 + 8 + c];
            const float syv = acc[b * 16 + 12 + c];
            loss += fmaxf(fp / (sxv + EPSV), fn / (syv + EPSV));
        }
    }
    out[0] = loss / 6.f;
}

extern "C" void kernel_launch(void* const* d_in, const int* in_sizes, int n_in,
                              void* d_out, int out_size, void* d_ws, size_t ws_size,
                              hipStream_t stream) {
    const float* x = (const float*)d_in[0];
    const int* y32 = (const int*)d_in[1];
    float* out = (float*)d_out;
    float* acc = (float*)d_ws;  // 32 floats

    hipMemsetAsync(d_ws, 0, 32 * sizeof(float), stream);
    mask_build<<<K0_NBLK, 256, 0, stream>>>(y32);
    lah_y<<<NBLK, 256, 0, stream>>>(x, acc);
    lah_finalize<<<1, 1, 0, stream>>>(acc, out);
}